// Round 4
// baseline (458.174 us; speedup 1.0000x reference)
//
#include <hip/hip_runtime.h>
#include <math.h>

// Problem constants (from reference): B=8, T=4096, D=2048, W=4, fp32 in/out.
#define CB 8
#define CT 4096
#define CD 2048
#define CW 4
#define TC 64          // t-steps per thread: halo = 3/64 ~ 4.7% extra reads.
                       // 512 blocks x 8 waves -> 2 blocks/CU -> 16 waves/CU
                       // (16 vs 32 waves measured neutral in rounds 0->1).
#define D4 (CD / 4)    // 512 float4 lanes across D == one full 8 KB row per block
#define NXCD 8

__device__ __forceinline__ float silu1(float v) {
    // v * sigmoid(v); sigmoid = rcp(1 + exp(-v)).  v_exp_f32 + v_rcp_f32 (~1 ulp).
    return v * __builtin_amdgcn_rcpf(1.f + __expf(-v));
}

__device__ __forceinline__ float4 conv_silu(const float4 w0, const float4 w1,
                                            const float4 w2, const float4 w3,
                                            const float4 a, const float4 b,
                                            const float4 c, const float4 d) {
    float4 r;
    r.x = silu1(w0.x * a.x + w1.x * b.x + w2.x * c.x + w3.x * d.x);
    r.y = silu1(w0.y * a.y + w1.y * b.y + w2.y * c.y + w3.y * d.y);
    r.z = silu1(w0.z * a.z + w1.z * b.z + w2.z * c.z + w3.z * d.z);
    r.w = silu1(w0.w * a.w + w1.w * b.w + w2.w * c.w + w3.w * d.w);
    return r;
}

// Block = 512 threads = full D row (8 KB). Each block owns a linear 512 KB
// output slab (64 contiguous t rows). XCD-bijective swizzle packs the 64
// t-chunks of each batch onto one XCD: the 3-row halo shared between
// t-adjacent chunks becomes an L2 hit instead of an HBM re-read, and each
// XCD's read stream covers one contiguous ~33 MB region (channel locality).
__global__ __launch_bounds__(512) void conv_silu_kernel(
    const float4* __restrict__ x,      // [B, T, D4]
    const float4* __restrict__ w,      // [W, D4]
    float4* __restrict__ out)          // [B, T, D4]
{
    // ---- XCD-bijective blockIdx swizzle (nwg = 512, nwg % 8 == 0) ----
    // Default dispatch round-robins consecutive blockIdx across the 8 XCDs.
    // Remap so that logical block l = xcd*64 + (orig/8): consecutive logical
    // blocks (t-adjacent chunks) share an XCD L2.
    const int nwg   = (CT / TC) * CB;          // 512
    const int orig  = blockIdx.x;
    const int lb    = (orig % NXCD) * (nwg / NXCD) + orig / NXCD;
    const int tchunks = CT / TC;               // 64
    const int b     = lb / tchunks;
    const int t0    = (lb % tchunks) * TC;

    const int d4 = threadIdx.x;                // 0..D4-1 (full row per block)

    const float4* xb = x   + (size_t)b * CT * D4 + d4;
    float4*       ob = out + (size_t)b * CT * D4 + d4;

    // Per-channel weights (4 float4 = 16 fp32), read once, L2-cached.
    const float4 w0 = w[0 * D4 + d4];
    const float4 w1 = w[1 * D4 + d4];
    const float4 w2 = w[2 * D4 + d4];
    const float4 w3 = w[3 * D4 + d4];

    // Rolling window x[t-3], x[t-2], x[t-1]. t0 is a multiple of TC (>=4),
    // so only the t0==0 chunk touches the causal zero-pad.
    float4 xm3 = make_float4(0.f, 0.f, 0.f, 0.f);
    float4 xm2 = xm3;
    float4 xm1 = xm3;
    if (t0 > 0) {
        xm3 = xb[(size_t)(t0 - 3) * D4];
        xm2 = xb[(size_t)(t0 - 2) * D4];
        xm1 = xb[(size_t)(t0 - 1) * D4];
    }

    // Software pipeline: issue group i+1's loads BEFORE group i's stores so
    // the vmcnt wait for the next compute never chains on store retirement
    // (loads and stores share the in-order vmcnt counter).
    size_t base = (size_t)t0 * D4;
    float4 c0 = xb[base + 0 * D4];
    float4 c1 = xb[base + 1 * D4];
    float4 c2 = xb[base + 2 * D4];
    float4 c3 = xb[base + 3 * D4];

#pragma unroll 1
    for (int t = t0; t < t0 + TC - 4; t += 4) {
        base = (size_t)t * D4;
        // Prefetch next group of 4 rows (independent of current compute).
        const float4 n0 = xb[base + 4 * D4];
        const float4 n1 = xb[base + 5 * D4];
        const float4 n2 = xb[base + 6 * D4];
        const float4 n3 = xb[base + 7 * D4];

        float4 y0 = conv_silu(w0, w1, w2, w3, xm3, xm2, xm1, c0);
        float4 y1 = conv_silu(w0, w1, w2, w3, xm2, xm1, c0,  c1);
        float4 y2 = conv_silu(w0, w1, w2, w3, xm1, c0,  c1,  c2);
        float4 y3 = conv_silu(w0, w1, w2, w3, c0,  c1,  c2,  c3);

        ob[base + 0 * D4] = y0;
        ob[base + 1 * D4] = y1;
        ob[base + 2 * D4] = y2;
        ob[base + 3 * D4] = y3;

        xm3 = c1; xm2 = c2; xm1 = c3;
        c0 = n0; c1 = n1; c2 = n2; c3 = n3;
    }

    // Epilogue: last group of 4 rows (already loaded).
    base = (size_t)(t0 + TC - 4) * D4;
    float4 y0 = conv_silu(w0, w1, w2, w3, xm3, xm2, xm1, c0);
    float4 y1 = conv_silu(w0, w1, w2, w3, xm2, xm1, c0,  c1);
    float4 y2 = conv_silu(w0, w1, w2, w3, xm1, c0,  c1,  c2);
    float4 y3 = conv_silu(w0, w1, w2, w3, c0,  c1,  c2,  c3);
    ob[base + 0 * D4] = y0;
    ob[base + 1 * D4] = y1;
    ob[base + 2 * D4] = y2;
    ob[base + 3 * D4] = y3;
}

extern "C" void kernel_launch(void* const* d_in, const int* in_sizes, int n_in,
                              void* d_out, int out_size, void* d_ws, size_t ws_size,
                              hipStream_t stream) {
    const float4* x = (const float4*)d_in[0];   // [B,T,D] fp32
    const float4* w = (const float4*)d_in[1];   // [W,1,D] fp32
    float4* out = (float4*)d_out;               // [B,T,D] fp32

    dim3 block(512);
    dim3 grid((CT / TC) * CB);                  // 512 blocks, 1-D for swizzle
    conv_silu_kernel<<<grid, block, 0, stream>>>(x, w, out);
}

// Round 5
// 437.632 us; speedup vs baseline: 1.0469x; 1.0469x over previous
//
#include <hip/hip_runtime.h>
#include <math.h>

// Problem constants (from reference): B=8, T=4096, D=2048, W=4, fp32 in/out.
// ROUND-5 NOTE: this is a pure revert to the round-3 best (436.9 us total,
// conv ~105 us). Falsified levers (do not retry): nontemporal stores (-15 us:
// store-ack chains through shared vmcnt), TC=64 + XCD-packing (-21 us:
// serializes a contiguous region behind one XCD's fabric port), occupancy
// 16 vs 32 waves (+-0), explicit SW pipeline (+-0 vs compiler), full-row vs
// half-row streams (+-0).
#define CB 8
#define CT 4096
#define CD 2048
#define CW 4
#define TC 32          // t-steps per thread: 1024 blocks x 8 waves -> 32 waves/CU
#define D4 (CD / 4)    // 512 float4 lanes across D == one full 8 KB row per block

__device__ __forceinline__ float silu1(float v) {
    // v * sigmoid(v); sigmoid = rcp(1 + exp(-v)).  v_exp_f32 + v_rcp_f32 (~1 ulp).
    return v * __builtin_amdgcn_rcpf(1.f + __expf(-v));
}

__device__ __forceinline__ float4 conv_silu(const float4 w0, const float4 w1,
                                            const float4 w2, const float4 w3,
                                            const float4 a, const float4 b,
                                            const float4 c, const float4 d) {
    float4 r;
    r.x = silu1(w0.x * a.x + w1.x * b.x + w2.x * c.x + w3.x * d.x);
    r.y = silu1(w0.y * a.y + w1.y * b.y + w2.y * c.y + w3.y * d.y);
    r.z = silu1(w0.z * a.z + w1.z * b.z + w2.z * c.z + w3.z * d.z);
    r.w = silu1(w0.w * a.w + w1.w * b.w + w2.w * c.w + w3.w * d.w);
    return r;
}

// Block = 512 threads = full D row (512 float4 = 8 KB = one row of x).
// Each block streams a dense linear 256 KB read slab (+24 KB halo prefix)
// and a dense linear 256 KB write slab. Default (round-robin) dispatch
// spreads concurrent blocks across all 8 XCD L2s — measured better than
// packing contiguous regions per-XCD.
__global__ __launch_bounds__(512) void conv_silu_kernel(
    const float4* __restrict__ x,      // [B, T, D4]
    const float4* __restrict__ w,      // [W, D4]
    float4* __restrict__ out)          // [B, T, D4]
{
    const int d4 = threadIdx.x;        // 0..D4-1 (full row per block)
    const int t0 = blockIdx.x * TC;
    const int b  = blockIdx.y;

    const float4* xb = x   + (size_t)b * CT * D4 + d4;
    float4*       ob = out + (size_t)b * CT * D4 + d4;

    // Per-channel weights (4 float4 = 16 fp32), read once, L2-cached.
    const float4 w0 = w[0 * D4 + d4];
    const float4 w1 = w[1 * D4 + d4];
    const float4 w2 = w[2 * D4 + d4];
    const float4 w3 = w[3 * D4 + d4];

    // Rolling window x[t-3], x[t-2], x[t-1]. t0 is a multiple of TC (>=4),
    // so only the t0==0 chunk touches the causal zero-pad.
    float4 xm3 = make_float4(0.f, 0.f, 0.f, 0.f);
    float4 xm2 = xm3;
    float4 xm1 = xm3;
    if (t0 > 0) {
        xm3 = xb[(size_t)(t0 - 3) * D4];
        xm2 = xb[(size_t)(t0 - 2) * D4];
        xm1 = xb[(size_t)(t0 - 1) * D4];
    }

    // Software pipeline: issue group i+1's loads BEFORE group i's stores so
    // the vmcnt wait for the next compute never chains on store retirement
    // (loads and stores share the in-order vmcnt counter).
    size_t base = (size_t)t0 * D4;
    float4 c0 = xb[base + 0 * D4];
    float4 c1 = xb[base + 1 * D4];
    float4 c2 = xb[base + 2 * D4];
    float4 c3 = xb[base + 3 * D4];

#pragma unroll 1
    for (int t = t0; t < t0 + TC - 4; t += 4) {
        base = (size_t)t * D4;
        // Prefetch next group of 4 rows (independent of current compute).
        const float4 n0 = xb[base + 4 * D4];
        const float4 n1 = xb[base + 5 * D4];
        const float4 n2 = xb[base + 6 * D4];
        const float4 n3 = xb[base + 7 * D4];

        float4 y0 = conv_silu(w0, w1, w2, w3, xm3, xm2, xm1, c0);
        float4 y1 = conv_silu(w0, w1, w2, w3, xm2, xm1, c0,  c1);
        float4 y2 = conv_silu(w0, w1, w2, w3, xm1, c0,  c1,  c2);
        float4 y3 = conv_silu(w0, w1, w2, w3, c0,  c1,  c2,  c3);

        ob[base + 0 * D4] = y0;
        ob[base + 1 * D4] = y1;
        ob[base + 2 * D4] = y2;
        ob[base + 3 * D4] = y3;

        xm3 = c1; xm2 = c2; xm1 = c3;
        c0 = n0; c1 = n1; c2 = n2; c3 = n3;
    }

    // Epilogue: last group of 4 rows (already loaded).
    base = (size_t)(t0 + TC - 4) * D4;
    float4 y0 = conv_silu(w0, w1, w2, w3, xm3, xm2, xm1, c0);
    float4 y1 = conv_silu(w0, w1, w2, w3, xm2, xm1, c0,  c1);
    float4 y2 = conv_silu(w0, w1, w2, w3, xm1, c0,  c1,  c2);
    float4 y3 = conv_silu(w0, w1, w2, w3, c0,  c1,  c2,  c3);
    ob[base + 0 * D4] = y0;
    ob[base + 1 * D4] = y1;
    ob[base + 2 * D4] = y2;
    ob[base + 3 * D4] = y3;
}

extern "C" void kernel_launch(void* const* d_in, const int* in_sizes, int n_in,
                              void* d_out, int out_size, void* d_ws, size_t ws_size,
                              hipStream_t stream) {
    const float4* x = (const float4*)d_in[0];   // [B,T,D] fp32
    const float4* w = (const float4*)d_in[1];   // [W,1,D] fp32
    float4* out = (float4*)d_out;               // [B,T,D] fp32

    dim3 block(512);
    dim3 grid(CT / TC, CB);                     // (128, 8) = 1024 blocks, 4/CU
    conv_silu_kernel<<<grid, block, 0, stream>>>(x, w, out);
}